// Round 8
// baseline (861.846 us; speedup 1.0000x reference)
//
#include <hip/hip_runtime.h>
#include <hip/hip_bf16.h>
#include <cstdio>
#include <cstdint>

#define T_TOK   8192
#define H_DIM   1024
#define I_DIM   2048
#define E_NUM   8
#define BM      128
#define BK2     32
#define PADMAX  17408         // T*K + E*BM
#define MAX_TILES 136         // T*K/BM + E

#define OUT_FRAC  8388608
#define OUT_AVG   8388616
#define OUT_LOG   8388624
#define OUT_PROB  8454160

typedef short short8v __attribute__((ext_vector_type(8)));
typedef float f32x4   __attribute__((ext_vector_type(4)));
typedef unsigned int u32x4 __attribute__((ext_vector_type(4)));

#define AS1 __attribute__((address_space(1)))
#define AS3 __attribute__((address_space(3)))
__device__ __forceinline__ void gload16(const void* g, void* l){
  __builtin_amdgcn_global_load_lds((const AS1 void*)g, (AS3 void*)l, 16, 0, 0);
}
// NT (non-temporal, evict-first) variant for zero-reuse streams: aux bit1 = NT
__device__ __forceinline__ void gload16nt(const void* g, void* l){
  __builtin_amdgcn_global_load_lds((const AS1 void*)g, (AS3 void*)l, 16, 0, 2);
}

#define WAITV5_BAR asm volatile("s_waitcnt vmcnt(5)\n\ts_barrier" ::: "memory")
#define WAITV3_BAR asm volatile("s_waitcnt vmcnt(3)\n\ts_barrier" ::: "memory")
#define WAITV0_BAR asm volatile("s_waitcnt vmcnt(0)\n\ts_barrier" ::: "memory")

__device__ __forceinline__ uint32_t f2bf(float f){
  union { float f; uint32_t u; } v; v.f = f;
  return (v.u + 0x7FFFu + ((v.u >> 16) & 1u)) >> 16;   // RNE
}
__device__ __forceinline__ uint32_t pack2(float a, float b){
  return f2bf(a) | (f2bf(b) << 16);
}
__device__ __forceinline__ float bflo(uint32_t u){ union{uint32_t u;float f;}v; v.u = u<<16; return v.f; }
__device__ __forceinline__ float bfhi(uint32_t u){ union{uint32_t u;float f;}v; v.u = u & 0xFFFF0000u; return v.f; }

// ---------------- fused fp32 -> bf16 bulk convert (x, gw, uw, dw), NT both sides ----------------
#define NXB  (T_TOK*H_DIM/2048)          // 4096
#define NWB  (E_NUM*I_DIM*H_DIM/2048)    // 8192
__global__ __launch_bounds__(256) void convert4_kernel(
    const float* __restrict__ x,  const float* __restrict__ gw,
    const float* __restrict__ uw, const float* __restrict__ dw,
    ushort* __restrict__ xb, ushort* __restrict__ gwb,
    ushort* __restrict__ uwb, ushort* __restrict__ dwb){
  const int b = blockIdx.x;
  const float* src; ushort* dst; size_t base;
  if (b < NXB)            { src = x;  dst = xb;  base = (size_t)b * 2048; }
  else if (b < NXB+NWB)   { src = gw; dst = gwb; base = (size_t)(b-NXB) * 2048; }
  else if (b < NXB+2*NWB) { src = uw; dst = uwb; base = (size_t)(b-NXB-NWB) * 2048; }
  else                    { src = dw; dst = dwb; base = (size_t)(b-NXB-2*NWB) * 2048; }
  size_t i = base + (size_t)threadIdx.x * 8;
  f32x4 f0 = __builtin_nontemporal_load((const f32x4*)(src + i));
  f32x4 f1 = __builtin_nontemporal_load((const f32x4*)(src + i + 4));
  u32x4 o;
  o.x = pack2(f0.x, f0.y); o.y = pack2(f0.z, f0.w);
  o.z = pack2(f1.x, f1.y); o.w = pack2(f1.z, f1.w);
  __builtin_nontemporal_store(o, (u32x4*)(dst + i));
}

// ---------------- router: logits/softmax/top2 ----------------
__global__ __launch_bounds__(256) void router_kernel(const float* __restrict__ x,
    const float* __restrict__ rw, float* __restrict__ out,
    int* __restrict__ counts, int* __restrict__ pe, float* __restrict__ pw){
  __shared__ float s_rw[E_NUM * H_DIM];
  __shared__ float s_avg[E_NUM];
  const int tid = threadIdx.x;
  for (int i = tid; i < E_NUM*H_DIM/4; i += 256)
    ((float4*)s_rw)[i] = ((const float4*)rw)[i];
  if (tid < E_NUM) s_avg[tid] = 0.f;
  __syncthreads();
  const int lane = tid & 63;
  const int t = blockIdx.x * 4 + (tid >> 6);
  float acc[E_NUM];
  #pragma unroll
  for (int e=0;e<E_NUM;e++) acc[e] = 0.f;
  const float* xr = x + (size_t)t * H_DIM;
  for (int c=0;c<H_DIM/64;c++){
    float xv = xr[c*64 + lane];
    #pragma unroll
    for (int e=0;e<E_NUM;e++) acc[e] += xv * s_rw[e*H_DIM + c*64 + lane];
  }
  #pragma unroll
  for (int e=0;e<E_NUM;e++){
    #pragma unroll
    for (int off=32; off; off>>=1) acc[e] += __shfl_xor(acc[e], off);
  }
  if (lane == 0){
    float m = acc[0];
    #pragma unroll
    for (int e=1;e<E_NUM;e++) m = fmaxf(m, acc[e]);
    float p[E_NUM]; float s = 0.f;
    #pragma unroll
    for (int e=0;e<E_NUM;e++){ p[e] = __expf(acc[e]-m); s += p[e]; }
    float inv = 1.f/s;
    #pragma unroll
    for (int e=0;e<E_NUM;e++) p[e] *= inv;
    float* lg = out + OUT_LOG  + (size_t)t*E_NUM;
    float* pr = out + OUT_PROB + (size_t)t*E_NUM;
    #pragma unroll
    for (int e=0;e<E_NUM;e++){ lg[e] = acc[e]; pr[e] = p[e]; }
    #pragma unroll
    for (int e=0;e<E_NUM;e++) atomicAdd(&s_avg[e], p[e]);
    int e1 = 0; float p1 = p[0];
    #pragma unroll
    for (int e=1;e<E_NUM;e++) if (p[e] > p1){ p1 = p[e]; e1 = e; }
    int e2 = -1; float p2 = -1.f;
    #pragma unroll
    for (int e=0;e<E_NUM;e++) if (e != e1 && p[e] > p2){ p2 = p[e]; e2 = e; }
    float rs = 1.f/(p1+p2);
    pe[2*t]   = e1; pw[2*t]   = p1*rs;
    pe[2*t+1] = e2; pw[2*t+1] = p2*rs;
    atomicAdd(&counts[e1], 1);
    atomicAdd(&counts[e2], 1);
  }
  __syncthreads();
  if (tid < E_NUM) atomicAdd(out + OUT_AVG + tid, s_avg[tid]);
}

// ---------------- offsets + tile table + zero-fill pads ----------------
__global__ void offsets_kernel(const int* __restrict__ counts, int* __restrict__ pad_off,
                               int* __restrict__ tile_e, int* __restrict__ tile_r,
                               int* __restrict__ hdr, int* __restrict__ s_tok,
                               float* __restrict__ s_wt){
  if (threadIdx.x == 0){
    int base = 0, tt = 0;
    for (int e=0;e<E_NUM;e++){
      pad_off[e] = base;
      int nt = (counts[e] + BM - 1) / BM;
      for (int i=0;i<nt;i++){ tile_e[tt] = e; tile_r[tt] = base + i*BM; tt++; }
      base += nt * BM;
    }
    hdr[0] = tt; hdr[1] = base;
  }
  for (int i = threadIdx.x; i < PADMAX; i += blockDim.x){
    s_tok[i] = 0; s_wt[i] = 0.f;
  }
}

// ---------------- scatter pairs into expert-sorted order ----------------
__global__ __launch_bounds__(256) void scatter_kernel(const int* __restrict__ pe,
    const float* __restrict__ pw, const int* __restrict__ pad_off,
    int* __restrict__ cursors, int* __restrict__ s_tok, float* __restrict__ s_wt,
    int* __restrict__ slot_idx){
  int t = blockIdx.x * 256 + threadIdx.x;
  #pragma unroll
  for (int k=0;k<2;k++){
    int e = pe[2*t + k];
    int pos = atomicAdd(&cursors[e], 1);
    int idx = pad_off[e] + pos;
    s_tok[idx] = t;
    s_wt[idx]  = pw[2*t + k];
    slot_idx[2*t + k] = idx;
  }
}

// ---------------- gate+up GEMM: BM=128 x BN=256, BK=32, 3-buf pipeline ----------------
// A stream (tokens) = NT; weights = cached (L2-resident panel per XCD column)
#define GU_STAGE(buf, kt) do {                                        \
    const int kof_ = (kt) * BK2;                                      \
    gload16nt(gA + kof_, &sA[buf][aBase]);                            \
    gload16(gG0 + kof_, &sG[buf][bBase0]);                            \
    gload16(gG1 + kof_, &sG[buf][bBase1]);                            \
    gload16(gU0 + kof_, &sU[buf][bBase0]);                            \
    gload16(gU1 + kof_, &sU[buf][bBase1]);                            \
  } while(0)

#define GU_COMPUTE(buf) do {                                          \
    short8v a_[4];                                                    \
    _Pragma("unroll") for (int mi=0;mi<4;mi++)                        \
      a_[mi] = *(const short8v*)&sA[buf][(wm + mi*16 + lr)*BK2 + swc]; \
    _Pragma("unroll") for (int ni=0;ni<4;ni++){                       \
      short8v bg = *(const short8v*)&sG[buf][(wn + ni*16 + lr)*BK2 + swc]; \
      short8v bu = *(const short8v*)&sU[buf][(wn + ni*16 + lr)*BK2 + swc]; \
      _Pragma("unroll") for (int mi=0;mi<4;mi++){                     \
        accG[mi][ni] = __builtin_amdgcn_mfma_f32_16x16x32_bf16(a_[mi], bg, accG[mi][ni], 0,0,0); \
        accU[mi][ni] = __builtin_amdgcn_mfma_f32_16x16x32_bf16(a_[mi], bu, accU[mi][ni], 0,0,0); \
      } } } while(0)

__global__ __launch_bounds__(512) void gateup_kernel(
    const ushort* __restrict__ xb, const ushort* __restrict__ gwb,
    const ushort* __restrict__ uwb, const int* __restrict__ s_tok,
    const int* __restrict__ tile_e, const int* __restrict__ tile_r,
    const int* __restrict__ hdr, ushort* __restrict__ h1)
{
  const int tile = blockIdx.y;
  if (tile >= hdr[0]) return;
  __shared__ short sA[3][BM*BK2];     // 8 KB each
  __shared__ short sG[3][256*BK2];    // 16 KB each
  __shared__ short sU[3][256*BK2];    // total 120 KB
  const int e = tile_e[tile];
  const int row0 = tile_r[tile];
  const int n0 = blockIdx.x * 256;
  const int tid = threadIdx.x, lane = tid & 63, wid = tid >> 6;

  const int srow = lane >> 2;
  const int scg  = ((lane & 3) ^ ((lane >> 3) & 3)) * 8;
  const int rowA  = wid*16 + srow;
  const int rowB0 = wid*32 + srow;
  const int rowB1 = wid*32 + 16 + srow;
  const ushort* gA  = xb  + (size_t)s_tok[row0 + rowA] * H_DIM + scg;
  const ushort* gG0 = gwb + ((size_t)e*I_DIM + n0 + rowB0) * H_DIM + scg;
  const ushort* gG1 = gwb + ((size_t)e*I_DIM + n0 + rowB1) * H_DIM + scg;
  const ushort* gU0 = uwb + ((size_t)e*I_DIM + n0 + rowB0) * H_DIM + scg;
  const ushort* gU1 = uwb + ((size_t)e*I_DIM + n0 + rowB1) * H_DIM + scg;
  const int aBase  = wid*16*BK2;
  const int bBase0 = wid*32*BK2;
  const int bBase1 = (wid*32+16)*BK2;

  const int wm = (wid >> 2) * 64, wn = (wid & 3) * 64;
  const int lr = lane & 15, q = lane >> 4;
  const int swc = (q ^ ((lr >> 1) & 3)) * 8;

  f32x4 accG[4][4] = {};
  f32x4 accU[4][4] = {};

  GU_STAGE(0, 0);
  GU_STAGE(1, 1);
  WAITV5_BAR;

  const int NK = H_DIM / BK2;   // 32
  int b0 = 0, b1 = 1, b2 = 2;
  for (int kt = 0; kt < NK; ++kt){
    if (kt + 2 < NK) GU_STAGE(b2, kt + 2);
    GU_COMPUTE(b0);
    if (kt + 2 < NK)      WAITV5_BAR;
    else if (kt + 1 < NK) WAITV0_BAR;
    int tb = b0; b0 = b1; b1 = b2; b2 = tb;
  }

  // epilogue: h1 = silu(g) * u  (bf16, NT stores)
  #pragma unroll
  for (int mi=0;mi<4;mi++){
    #pragma unroll
    for (int r=0;r<4;r++){
      const int row = row0 + wm + mi*16 + q*4 + r;
      ushort* hp = h1 + (size_t)row * I_DIM + n0 + wn + lr;
      #pragma unroll
      for (int ni=0;ni<4;ni++){
        float g = accG[mi][ni][r], u = accU[mi][ni][r];
        float sv = g / (1.f + __expf(-g));
        __builtin_nontemporal_store((ushort)f2bf(sv * u), hp + ni*16);
      }
    }
  }
}

// ---------------- down GEMM: BM=128 x BN=256, BK=32, 3-buf pipeline ----------------
#define DN_STAGE(buf, kt) do {                                        \
    const int kof_ = (kt) * BK2;                                      \
    gload16nt(gA + kof_, &sA[buf][aBase]);                            \
    gload16(gB0 + kof_, &sB[buf][bBase0]);                            \
    gload16(gB1 + kof_, &sB[buf][bBase1]);                            \
  } while(0)

#define DN_COMPUTE(buf) do {                                          \
    short8v a_[4];                                                    \
    _Pragma("unroll") for (int mi=0;mi<4;mi++)                        \
      a_[mi] = *(const short8v*)&sA[buf][(wm + mi*16 + lr)*BK2 + swc]; \
    _Pragma("unroll") for (int ni=0;ni<4;ni++){                       \
      short8v b = *(const short8v*)&sB[buf][(wn + ni*16 + lr)*BK2 + swc]; \
      _Pragma("unroll") for (int mi=0;mi<4;mi++)                      \
        acc[mi][ni] = __builtin_amdgcn_mfma_f32_16x16x32_bf16(a_[mi], b, acc[mi][ni], 0,0,0); \
    } } while(0)

__global__ __launch_bounds__(512) void down_kernel(
    const ushort* __restrict__ h1, const ushort* __restrict__ dwb,
    const int* __restrict__ tile_e, const int* __restrict__ tile_r,
    const int* __restrict__ hdr, ushort* __restrict__ ds_out)
{
  const int tile = blockIdx.y;
  if (tile >= hdr[0]) return;
  __shared__ short sA[3][BM*BK2];     // 8 KB each
  __shared__ short sB[3][256*BK2];    // 16 KB each — total 72 KB
  const int e = tile_e[tile];
  const int row0 = tile_r[tile];
  const int n0 = blockIdx.x * 256;
  const int tid = threadIdx.x, lane = tid & 63, wid = tid >> 6;

  const int srow = lane >> 2;
  const int scg  = ((lane & 3) ^ ((lane >> 3) & 3)) * 8;
  const int rowA  = wid*16 + srow;
  const int rowB0 = wid*32 + srow;
  const int rowB1 = wid*32 + 16 + srow;
  const ushort* gA  = h1  + (size_t)(row0 + rowA) * I_DIM + scg;
  const ushort* gB0 = dwb + ((size_t)e*H_DIM + n0 + rowB0) * I_DIM + scg;
  const ushort* gB1 = dwb + ((size_t)e*H_DIM + n0 + rowB1) * I_DIM + scg;
  const int aBase  = wid*16*BK2;
  const int bBase0 = wid*32*BK2;
  const int bBase1 = (wid*32+16)*BK2;

  const int wm = (wid >> 2) * 64, wn = (wid & 3) * 64;
  const int lr = lane & 15, q = lane >> 4;
  const int swc = (q ^ ((lr >> 1) & 3)) * 8;

  f32x4 acc[4][4] = {};

  DN_STAGE(0, 0);
  DN_STAGE(1, 1);
  WAITV3_BAR;

  const int NK = I_DIM / BK2;   // 64
  int b0 = 0, b1 = 1, b2 = 2;
  for (int kt = 0; kt < NK; ++kt){
    if (kt + 2 < NK) DN_STAGE(b2, kt + 2);
    DN_COMPUTE(b0);
    if (kt + 2 < NK)      WAITV3_BAR;
    else if (kt + 1 < NK) WAITV0_BAR;
    int tb = b0; b0 = b1; b1 = b2; b2 = tb;
  }

  #pragma unroll
  for (int mi=0;mi<4;mi++){
    #pragma unroll
    for (int r=0;r<4;r++){
      const int prow = row0 + wm + mi*16 + q*4 + r;
      ushort* op = ds_out + (size_t)prow * H_DIM + n0 + wn + lr;
      #pragma unroll
      for (int ni=0;ni<4;ni++)
        __builtin_nontemporal_store((ushort)f2bf(acc[mi][ni][r]), op + ni*16);
    }
  }
}

// ---------------- combine: out[t] = w1*ds[s1] + w2*ds[s2] ----------------
__global__ __launch_bounds__(256) void combine_kernel(const ushort* __restrict__ ds_out,
    const int* __restrict__ slot_idx, const float* __restrict__ s_wt,
    float* __restrict__ out){
  const int t   = blockIdx.x * 2 + (threadIdx.x >> 7);
  const int col = (threadIdx.x & 127) * 8;
  const int s1 = slot_idx[2*t], s2 = slot_idx[2*t+1];
  const float w1 = s_wt[s1], w2 = s_wt[s2];
  const u32x4 a = __builtin_nontemporal_load((const u32x4*)(ds_out + (size_t)s1 * H_DIM + col));
  const u32x4 b = __builtin_nontemporal_load((const u32x4*)(ds_out + (size_t)s2 * H_DIM + col));
  float* op = out + (size_t)t * H_DIM + col;
  f32x4 o0, o1;
  o0.x = w1*bflo(a.x) + w2*bflo(b.x);
  o0.y = w1*bfhi(a.x) + w2*bfhi(b.x);
  o0.z = w1*bflo(a.y) + w2*bflo(b.y);
  o0.w = w1*bfhi(a.y) + w2*bfhi(b.y);
  o1.x = w1*bflo(a.z) + w2*bflo(b.z);
  o1.y = w1*bfhi(a.z) + w2*bfhi(b.z);
  o1.z = w1*bflo(a.w) + w2*bflo(b.w);
  o1.w = w1*bfhi(a.w) + w2*bfhi(b.w);
  __builtin_nontemporal_store(o0, (f32x4*)op);
  __builtin_nontemporal_store(o1, (f32x4*)(op + 4));
}

// ---------------- finalize expert_frac / avg_prob ----------------
__global__ void finalize_kernel(const int* __restrict__ counts, float* __restrict__ out){
  int t = threadIdx.x;
  if (t < E_NUM){
    out[OUT_FRAC + t] = (float)counts[t] * (1.f/16384.f);
    out[OUT_AVG  + t] *= (1.f/8192.f);
  }
}

extern "C" void kernel_launch(void* const* d_in, const int* in_sizes, int n_in,
                              void* d_out, int out_size, void* d_ws, size_t ws_size,
                              hipStream_t stream){
  const float* x   = (const float*)d_in[0];
  const float* rw  = (const float*)d_in[1];
  const float* gw  = (const float*)d_in[2];
  const float* uw  = (const float*)d_in[3];
  const float* dwn = (const float*)d_in[4];
  float* out = (float*)d_out;

  char* w = (char*)d_ws;
  int*   counts   = (int*)(w + 0);
  int*   cursors  = (int*)(w + 32);
  int*   hdr      = (int*)(w + 64);
  int*   pad_off  = (int*)(w + 96);
  int*   tile_e   = (int*)(w + 256);
  int*   tile_r   = (int*)(w + 1024);
  int*   s_tok    = (int*)(w + 4096);
  float* s_wt     = (float*)(w + 4096 + PADMAX*4);
  int*   pe       = (int*)(w + 4096 + PADMAX*8);
  float* pw       = (float*)(w + 4096 + PADMAX*8 + T_TOK*2*4);
  int*   slot_idx = (int*)(w + 4096 + PADMAX*8 + T_TOK*2*8);
  ushort* xb      = (ushort*)(w + 339968);
  ushort* h1      = (ushort*)(w + 339968 + (size_t)T_TOK*H_DIM*2);
  ushort* gwb     = (ushort*)(w + 339968 + (size_t)T_TOK*H_DIM*2 + (size_t)PADMAX*I_DIM*2);
  ushort* uwb     = gwb + (size_t)E_NUM*I_DIM*H_DIM;
  ushort* dwb     = uwb + (size_t)E_NUM*I_DIM*H_DIM;
  ushort* ds_out  = gwb;   // overlay: gwb/uwb are dead once gateup completes

  size_t need = 339968 + (size_t)T_TOK*H_DIM*2 + (size_t)PADMAX*I_DIM*2
              + 3ull * E_NUM*I_DIM*H_DIM * 2;
  if (ws_size < need){
    fprintf(stderr, "kernel_launch: ws too small (%zu < %zu)\n", ws_size, need);
    return;
  }

  hipMemsetAsync(out + OUT_FRAC, 0, (OUT_AVG + E_NUM - OUT_FRAC) * 4, stream);
  hipMemsetAsync(d_ws, 0, 4096, stream);
  convert4_kernel<<<NXB + 3*NWB, 256, 0, stream>>>(x, gw, uw, dwn, xb, gwb, uwb, dwb);
  router_kernel<<<T_TOK/4, 256, 0, stream>>>(x, rw, out, counts, pe, pw);
  offsets_kernel<<<1, 256, 0, stream>>>(counts, pad_off, tile_e, tile_r, hdr, s_tok, s_wt);
  scatter_kernel<<<T_TOK/256, 256, 0, stream>>>(pe, pw, pad_off, cursors, s_tok, s_wt, slot_idx);
  gateup_kernel<<<dim3(I_DIM/256, MAX_TILES), 512, 0, stream>>>(xb, gwb, uwb, s_tok, tile_e, tile_r, hdr, h1);
  down_kernel<<<dim3(H_DIM/256, MAX_TILES), 512, 0, stream>>>(h1, dwb, tile_e, tile_r, hdr, ds_out);
  combine_kernel<<<T_TOK/2, 256, 0, stream>>>(ds_out, slot_idx, s_wt, out);
  finalize_kernel<<<1, 64, 0, stream>>>(counts, out);
}

// Round 9
// 646.213 us; speedup vs baseline: 1.3337x; 1.3337x over previous
//
#include <hip/hip_runtime.h>
#include <hip/hip_bf16.h>
#include <cstdio>
#include <cstdint>

#define T_TOK   8192
#define H_DIM   1024
#define I_DIM   2048
#define E_NUM   8
#define BM      128
#define BK2     32
#define PADMAX  17408         // T*K + E*BM
#define MAX_TILES 136         // T*K/BM + E

#define OUT_FRAC  8388608
#define OUT_AVG   8388616
#define OUT_LOG   8388624
#define OUT_PROB  8454160

typedef short short8v __attribute__((ext_vector_type(8)));
typedef float f32x4   __attribute__((ext_vector_type(4)));
typedef unsigned int u32x4 __attribute__((ext_vector_type(4)));

#define AS1 __attribute__((address_space(1)))
#define AS3 __attribute__((address_space(3)))
__device__ __forceinline__ void gload16(const void* g, void* l){
  __builtin_amdgcn_global_load_lds((const AS1 void*)g, (AS3 void*)l, 16, 0, 0);
}

#define WAITV5_BAR asm volatile("s_waitcnt vmcnt(5)\n\ts_barrier" ::: "memory")
#define WAITV3_BAR asm volatile("s_waitcnt vmcnt(3)\n\ts_barrier" ::: "memory")
#define WAITV0_BAR asm volatile("s_waitcnt vmcnt(0)\n\ts_barrier" ::: "memory")
#define SBAR  __builtin_amdgcn_s_barrier()
#define SCHED0 __builtin_amdgcn_sched_barrier(0)

__device__ __forceinline__ uint32_t f2bf(float f){
  union { float f; uint32_t u; } v; v.f = f;
  return (v.u + 0x7FFFu + ((v.u >> 16) & 1u)) >> 16;   // RNE
}
__device__ __forceinline__ uint32_t pack2(float a, float b){
  return f2bf(a) | (f2bf(b) << 16);
}
__device__ __forceinline__ float bflo(uint32_t u){ union{uint32_t u;float f;}v; v.u = u<<16; return v.f; }
__device__ __forceinline__ float bfhi(uint32_t u){ union{uint32_t u;float f;}v; v.u = u & 0xFFFF0000u; return v.f; }

// ---------------- fused fp32 -> bf16 bulk convert (x, gw, uw, dw) ----------------
#define NXB  (T_TOK*H_DIM/2048)          // 4096
#define NWB  (E_NUM*I_DIM*H_DIM/2048)    // 8192
__global__ __launch_bounds__(256) void convert4_kernel(
    const float* __restrict__ x,  const float* __restrict__ gw,
    const float* __restrict__ uw, const float* __restrict__ dw,
    ushort* __restrict__ xb, ushort* __restrict__ gwb,
    ushort* __restrict__ uwb, ushort* __restrict__ dwb){
  const int b = blockIdx.x;
  const float* src; ushort* dst; size_t base;
  if (b < NXB)            { src = x;  dst = xb;  base = (size_t)b * 2048; }
  else if (b < NXB+NWB)   { src = gw; dst = gwb; base = (size_t)(b-NXB) * 2048; }
  else if (b < NXB+2*NWB) { src = uw; dst = uwb; base = (size_t)(b-NXB-NWB) * 2048; }
  else                    { src = dw; dst = dwb; base = (size_t)(b-NXB-2*NWB) * 2048; }
  size_t i = base + (size_t)threadIdx.x * 8;
  f32x4 f0 = *(const f32x4*)(src + i);
  f32x4 f1 = *(const f32x4*)(src + i + 4);
  u32x4 o;
  o.x = pack2(f0.x, f0.y); o.y = pack2(f0.z, f0.w);
  o.z = pack2(f1.x, f1.y); o.w = pack2(f1.z, f1.w);
  *(u32x4*)(dst + i) = o;
}

// ---------------- router: logits/softmax/top2 ----------------
__global__ __launch_bounds__(256) void router_kernel(const float* __restrict__ x,
    const float* __restrict__ rw, float* __restrict__ out,
    int* __restrict__ counts, int* __restrict__ pe, float* __restrict__ pw){
  __shared__ float s_rw[E_NUM * H_DIM];
  __shared__ float s_avg[E_NUM];
  const int tid = threadIdx.x;
  for (int i = tid; i < E_NUM*H_DIM/4; i += 256)
    ((float4*)s_rw)[i] = ((const float4*)rw)[i];
  if (tid < E_NUM) s_avg[tid] = 0.f;
  __syncthreads();
  const int lane = tid & 63;
  const int t = blockIdx.x * 4 + (tid >> 6);
  float acc[E_NUM];
  #pragma unroll
  for (int e=0;e<E_NUM;e++) acc[e] = 0.f;
  const float* xr = x + (size_t)t * H_DIM;
  for (int c=0;c<H_DIM/64;c++){
    float xv = xr[c*64 + lane];
    #pragma unroll
    for (int e=0;e<E_NUM;e++) acc[e] += xv * s_rw[e*H_DIM + c*64 + lane];
  }
  #pragma unroll
  for (int e=0;e<E_NUM;e++){
    #pragma unroll
    for (int off=32; off; off>>=1) acc[e] += __shfl_xor(acc[e], off);
  }
  if (lane == 0){
    float m = acc[0];
    #pragma unroll
    for (int e=1;e<E_NUM;e++) m = fmaxf(m, acc[e]);
    float p[E_NUM]; float s = 0.f;
    #pragma unroll
    for (int e=0;e<E_NUM;e++){ p[e] = __expf(acc[e]-m); s += p[e]; }
    float inv = 1.f/s;
    #pragma unroll
    for (int e=0;e<E_NUM;e++) p[e] *= inv;
    float* lg = out + OUT_LOG  + (size_t)t*E_NUM;
    float* pr = out + OUT_PROB + (size_t)t*E_NUM;
    #pragma unroll
    for (int e=0;e<E_NUM;e++){ lg[e] = acc[e]; pr[e] = p[e]; }
    #pragma unroll
    for (int e=0;e<E_NUM;e++) atomicAdd(&s_avg[e], p[e]);
    int e1 = 0; float p1 = p[0];
    #pragma unroll
    for (int e=1;e<E_NUM;e++) if (p[e] > p1){ p1 = p[e]; e1 = e; }
    int e2 = -1; float p2 = -1.f;
    #pragma unroll
    for (int e=0;e<E_NUM;e++) if (e != e1 && p[e] > p2){ p2 = p[e]; e2 = e; }
    float rs = 1.f/(p1+p2);
    pe[2*t]   = e1; pw[2*t]   = p1*rs;
    pe[2*t+1] = e2; pw[2*t+1] = p2*rs;
    atomicAdd(&counts[e1], 1);
    atomicAdd(&counts[e2], 1);
  }
  __syncthreads();
  if (tid < E_NUM) atomicAdd(out + OUT_AVG + tid, s_avg[tid]);
}

// ---------------- offsets + tile table + zero-fill pads ----------------
__global__ void offsets_kernel(const int* __restrict__ counts, int* __restrict__ pad_off,
                               int* __restrict__ tile_e, int* __restrict__ tile_r,
                               int* __restrict__ hdr, int* __restrict__ s_tok,
                               float* __restrict__ s_wt){
  if (threadIdx.x == 0){
    int base = 0, tt = 0;
    for (int e=0;e<E_NUM;e++){
      pad_off[e] = base;
      int nt = (counts[e] + BM - 1) / BM;
      for (int i=0;i<nt;i++){ tile_e[tt] = e; tile_r[tt] = base + i*BM; tt++; }
      base += nt * BM;
    }
    hdr[0] = tt; hdr[1] = base;
  }
  for (int i = threadIdx.x; i < PADMAX; i += blockDim.x){
    s_tok[i] = 0; s_wt[i] = 0.f;
  }
}

// ---------------- scatter pairs into expert-sorted order ----------------
__global__ __launch_bounds__(256) void scatter_kernel(const int* __restrict__ pe,
    const float* __restrict__ pw, const int* __restrict__ pad_off,
    int* __restrict__ cursors, int* __restrict__ s_tok, float* __restrict__ s_wt,
    int* __restrict__ slot_idx){
  int t = blockIdx.x * 256 + threadIdx.x;
  #pragma unroll
  for (int k=0;k<2;k++){
    int e = pe[2*t + k];
    int pos = atomicAdd(&cursors[e], 1);
    int idx = pad_off[e] + pos;
    s_tok[idx] = t;
    s_wt[idx]  = pw[2*t + k];
    slot_idx[2*t + k] = idx;
  }
}

// ---------------- gate+up GEMM: BM=128 x BN=256, BK=32, 3-buf, 2 fine phases/step ----------------
__global__ __launch_bounds__(512, 2) void gateup_kernel(
    const ushort* __restrict__ xb, const ushort* __restrict__ gwb,
    const ushort* __restrict__ uwb, const int* __restrict__ s_tok,
    const int* __restrict__ tile_e, const int* __restrict__ tile_r,
    const int* __restrict__ hdr, ushort* __restrict__ h1)
{
  const int tile = blockIdx.y;
  if (tile >= hdr[0]) return;
  __shared__ short sA[3][BM*BK2];     // 8 KB each
  __shared__ short sG[3][256*BK2];    // 16 KB each
  __shared__ short sU[3][256*BK2];    // total 120 KB
  const int e = tile_e[tile];
  const int row0 = tile_r[tile];
  const int n0 = blockIdx.x * 256;
  const int tid = threadIdx.x, lane = tid & 63, wid = tid >> 6;

  // staging: lane -> row = base + lane>>2, lds chunk = lane&3; source chunk xor'd
  const int srow = lane >> 2;
  const int scg  = ((lane & 3) ^ ((lane >> 3) & 3)) * 8;
  const int rowA  = wid*16 + srow;
  const int rowB0 = wid*32 + srow;
  const int rowB1 = wid*32 + 16 + srow;
  const ushort* gA  = xb  + (size_t)s_tok[row0 + rowA] * H_DIM + scg;
  const ushort* gG0 = gwb + ((size_t)e*I_DIM + n0 + rowB0) * H_DIM + scg;
  const ushort* gG1 = gwb + ((size_t)e*I_DIM + n0 + rowB1) * H_DIM + scg;
  const ushort* gU0 = uwb + ((size_t)e*I_DIM + n0 + rowB0) * H_DIM + scg;
  const ushort* gU1 = uwb + ((size_t)e*I_DIM + n0 + rowB1) * H_DIM + scg;
  const int aBase  = wid*16*BK2;
  const int bBase0 = wid*32*BK2;
  const int bBase1 = (wid*32+16)*BK2;

  const int wm = (wid >> 2) * 64, wn = (wid & 3) * 64;
  const int lr = lane & 15, q = lane >> 4;
  const int swc = (q ^ ((lr >> 1) & 3)) * 8;

  f32x4 accG[4][4] = {};
  f32x4 accU[4][4] = {};

  // prologue: stage tiles 0 and 1
  {
    gload16(gA,        &sA[0][aBase]);
    gload16(gG0,       &sG[0][bBase0]);
    gload16(gG1,       &sG[0][bBase1]);
    gload16(gU0,       &sU[0][bBase0]);
    gload16(gU1,       &sU[0][bBase1]);
    gload16(gA  + BK2, &sA[1][aBase]);
    gload16(gG0 + BK2, &sG[1][bBase0]);
    gload16(gG1 + BK2, &sG[1][bBase1]);
    gload16(gU0 + BK2, &sU[1][bBase0]);
    gload16(gU1 + BK2, &sU[1][bBase1]);
  }
  WAITV5_BAR;   // tile0 complete; tile1 in flight

  const int NK = H_DIM / BK2;   // 32
  int b0 = 0, b1 = 1, b2 = 2;
  for (int kt = 0; kt < NK; ++kt){
    short8v a_[4], bg_[4], bu_[4];
    // ---- phase 1: A+G reads, stage A,G of kt+2, MFMA accG ----
    #pragma unroll
    for (int mi=0;mi<4;mi++)
      a_[mi] = *(const short8v*)&sA[b0][(wm + mi*16 + lr)*BK2 + swc];
    #pragma unroll
    for (int ni=0;ni<4;ni++)
      bg_[ni] = *(const short8v*)&sG[b0][(wn + ni*16 + lr)*BK2 + swc];
    if (kt + 2 < NK){
      const int kof = (kt+2)*BK2;
      gload16(gA  + kof, &sA[b2][aBase]);
      gload16(gG0 + kof, &sG[b2][bBase0]);
      gload16(gG1 + kof, &sG[b2][bBase1]);
    }
    SCHED0; SBAR; SCHED0;
    __builtin_amdgcn_s_setprio(1);
    #pragma unroll
    for (int ni=0;ni<4;ni++)
      #pragma unroll
      for (int mi=0;mi<4;mi++)
        accG[mi][ni] = __builtin_amdgcn_mfma_f32_16x16x32_bf16(a_[mi], bg_[ni], accG[mi][ni], 0,0,0);
    __builtin_amdgcn_s_setprio(0);
    SCHED0; SBAR;
    // ---- phase 2: U reads, stage U of kt+2, MFMA accU ----
    #pragma unroll
    for (int ni=0;ni<4;ni++)
      bu_[ni] = *(const short8v*)&sU[b0][(wn + ni*16 + lr)*BK2 + swc];
    if (kt + 2 < NK){
      const int kof = (kt+2)*BK2;
      gload16(gU0 + kof, &sU[b2][bBase0]);
      gload16(gU1 + kof, &sU[b2][bBase1]);
    }
    SCHED0; SBAR; SCHED0;
    __builtin_amdgcn_s_setprio(1);
    #pragma unroll
    for (int ni=0;ni<4;ni++)
      #pragma unroll
      for (int mi=0;mi<4;mi++)
        accU[mi][ni] = __builtin_amdgcn_mfma_f32_16x16x32_bf16(a_[mi], bu_[ni], accU[mi][ni], 0,0,0);
    __builtin_amdgcn_s_setprio(0);
    SCHED0;
    if (kt + 2 < NK)      WAITV5_BAR;   // kt+1 ready; kt+2 (5 loads) in flight
    else if (kt + 1 < NK) WAITV0_BAR;   // drain last prefetch
    int tb = b0; b0 = b1; b1 = b2; b2 = tb;
  }

  // epilogue: h1 = silu(g) * u  (bf16)
  #pragma unroll
  for (int mi=0;mi<4;mi++){
    #pragma unroll
    for (int r=0;r<4;r++){
      const int row = row0 + wm + mi*16 + q*4 + r;
      ushort* hp = h1 + (size_t)row * I_DIM + n0 + wn + lr;
      #pragma unroll
      for (int ni=0;ni<4;ni++){
        float g = accG[mi][ni][r], u = accU[mi][ni][r];
        float sv = g / (1.f + __expf(-g));
        hp[ni*16] = (ushort)f2bf(sv * u);
      }
    }
  }
}

// ---------------- down GEMM: BM=128 x BN=256, BK=32, 3-buf, 2 fine phases/step ----------------
__global__ __launch_bounds__(512, 2) void down_kernel(
    const ushort* __restrict__ h1, const ushort* __restrict__ dwb,
    const int* __restrict__ tile_e, const int* __restrict__ tile_r,
    const int* __restrict__ hdr, ushort* __restrict__ ds_out)
{
  const int tile = blockIdx.y;
  if (tile >= hdr[0]) return;
  __shared__ short sA[3][BM*BK2];     // 8 KB each
  __shared__ short sB[3][256*BK2];    // 16 KB each — total 72 KB
  const int e = tile_e[tile];
  const int row0 = tile_r[tile];
  const int n0 = blockIdx.x * 256;
  const int tid = threadIdx.x, lane = tid & 63, wid = tid >> 6;

  const int srow = lane >> 2;
  const int scg  = ((lane & 3) ^ ((lane >> 3) & 3)) * 8;
  const int rowA  = wid*16 + srow;
  const int rowB0 = wid*32 + srow;
  const int rowB1 = wid*32 + 16 + srow;
  const ushort* gA  = h1  + (size_t)(row0 + rowA) * I_DIM + scg;
  const ushort* gB0 = dwb + ((size_t)e*H_DIM + n0 + rowB0) * I_DIM + scg;
  const ushort* gB1 = dwb + ((size_t)e*H_DIM + n0 + rowB1) * I_DIM + scg;
  const int aBase  = wid*16*BK2;
  const int bBase0 = wid*32*BK2;
  const int bBase1 = (wid*32+16)*BK2;

  const int wm = (wid >> 2) * 64, wn = (wid & 3) * 64;
  const int lr = lane & 15, q = lane >> 4;
  const int swc = (q ^ ((lr >> 1) & 3)) * 8;

  f32x4 acc[4][4] = {};

  {
    gload16(gA,        &sA[0][aBase]);
    gload16(gB0,       &sB[0][bBase0]);
    gload16(gB1,       &sB[0][bBase1]);
    gload16(gA  + BK2, &sA[1][aBase]);
    gload16(gB0 + BK2, &sB[1][bBase0]);
    gload16(gB1 + BK2, &sB[1][bBase1]);
  }
  WAITV3_BAR;

  const int NK = I_DIM / BK2;   // 64
  int b0 = 0, b1 = 1, b2 = 2;
  for (int kt = 0; kt < NK; ++kt){
    short8v a_[4], b_[4];
    // ---- phase 1: A + B[0..1] reads, stage A,B0 of kt+2, 8 MFMA ----
    #pragma unroll
    for (int mi=0;mi<4;mi++)
      a_[mi] = *(const short8v*)&sA[b0][(wm + mi*16 + lr)*BK2 + swc];
    #pragma unroll
    for (int ni=0;ni<2;ni++)
      b_[ni] = *(const short8v*)&sB[b0][(wn + ni*16 + lr)*BK2 + swc];
    if (kt + 2 < NK){
      const int kof = (kt+2)*BK2;
      gload16(gA  + kof, &sA[b2][aBase]);
      gload16(gB0 + kof, &sB[b2][bBase0]);
    }
    SCHED0; SBAR; SCHED0;
    __builtin_amdgcn_s_setprio(1);
    #pragma unroll
    for (int ni=0;ni<2;ni++)
      #pragma unroll
      for (int mi=0;mi<4;mi++)
        acc[mi][ni] = __builtin_amdgcn_mfma_f32_16x16x32_bf16(a_[mi], b_[ni], acc[mi][ni], 0,0,0);
    __builtin_amdgcn_s_setprio(0);
    SCHED0; SBAR;
    // ---- phase 2: B[2..3] reads, stage B1 of kt+2, 8 MFMA ----
    #pragma unroll
    for (int ni=2;ni<4;ni++)
      b_[ni] = *(const short8v*)&sB[b0][(wn + ni*16 + lr)*BK2 + swc];
    if (kt + 2 < NK){
      const int kof = (kt+2)*BK2;
      gload16(gB1 + kof, &sB[b2][bBase1]);
    }
    SCHED0; SBAR; SCHED0;
    __builtin_amdgcn_s_setprio(1);
    #pragma unroll
    for (int ni=2;ni<4;ni++)
      #pragma unroll
      for (int mi=0;mi<4;mi++)
        acc[mi][ni] = __builtin_amdgcn_mfma_f32_16x16x32_bf16(a_[mi], b_[ni], acc[mi][ni], 0,0,0);
    __builtin_amdgcn_s_setprio(0);
    SCHED0;
    if (kt + 2 < NK)      WAITV3_BAR;
    else if (kt + 1 < NK) WAITV0_BAR;
    int tb = b0; b0 = b1; b1 = b2; b2 = tb;
  }

  #pragma unroll
  for (int mi=0;mi<4;mi++){
    #pragma unroll
    for (int r=0;r<4;r++){
      const int prow = row0 + wm + mi*16 + q*4 + r;
      ushort* op = ds_out + (size_t)prow * H_DIM + n0 + wn + lr;
      #pragma unroll
      for (int ni=0;ni<4;ni++)
        op[ni*16] = (ushort)f2bf(acc[mi][ni][r]);
    }
  }
}

// ---------------- combine: out[t] = w1*ds[s1] + w2*ds[s2] ----------------
__global__ __launch_bounds__(256) void combine_kernel(const ushort* __restrict__ ds_out,
    const int* __restrict__ slot_idx, const float* __restrict__ s_wt,
    float* __restrict__ out){
  const int t   = blockIdx.x * 2 + (threadIdx.x >> 7);
  const int col = (threadIdx.x & 127) * 8;
  const int s1 = slot_idx[2*t], s2 = slot_idx[2*t+1];
  const float w1 = s_wt[s1], w2 = s_wt[s2];
  const u32x4 a = *(const u32x4*)(ds_out + (size_t)s1 * H_DIM + col);
  const u32x4 b = *(const u32x4*)(ds_out + (size_t)s2 * H_DIM + col);
  float* op = out + (size_t)t * H_DIM + col;
  f32x4 o0, o1;
  o0.x = w1*bflo(a.x) + w2*bflo(b.x);
  o0.y = w1*bfhi(a.x) + w2*bfhi(b.x);
  o0.z = w1*bflo(a.y) + w2*bflo(b.y);
  o0.w = w1*bfhi(a.y) + w2*bfhi(b.y);
  o1.x = w1*bflo(a.z) + w2*bflo(b.z);
  o1.y = w1*bfhi(a.z) + w2*bfhi(b.z);
  o1.z = w1*bflo(a.w) + w2*bflo(b.w);
  o1.w = w1*bfhi(a.w) + w2*bfhi(b.w);
  *(f32x4*)op       = o0;
  *(f32x4*)(op + 4) = o1;
}

// ---------------- finalize expert_frac / avg_prob ----------------
__global__ void finalize_kernel(const int* __restrict__ counts, float* __restrict__ out){
  int t = threadIdx.x;
  if (t < E_NUM){
    out[OUT_FRAC + t] = (float)counts[t] * (1.f/16384.f);
    out[OUT_AVG  + t] *= (1.f/8192.f);
  }
}

extern "C" void kernel_launch(void* const* d_in, const int* in_sizes, int n_in,
                              void* d_out, int out_size, void* d_ws, size_t ws_size,
                              hipStream_t stream){
  const float* x   = (const float*)d_in[0];
  const float* rw  = (const float*)d_in[1];
  const float* gw  = (const float*)d_in[2];
  const float* uw  = (const float*)d_in[3];
  const float* dwn = (const float*)d_in[4];
  float* out = (float*)d_out;

  char* w = (char*)d_ws;
  int*   counts   = (int*)(w + 0);
  int*   cursors  = (int*)(w + 32);
  int*   hdr      = (int*)(w + 64);
  int*   pad_off  = (int*)(w + 96);
  int*   tile_e   = (int*)(w + 256);
  int*   tile_r   = (int*)(w + 1024);
  int*   s_tok    = (int*)(w + 4096);
  float* s_wt     = (float*)(w + 4096 + PADMAX*4);
  int*   pe       = (int*)(w + 4096 + PADMAX*8);
  float* pw       = (float*)(w + 4096 + PADMAX*8 + T_TOK*2*4);
  int*   slot_idx = (int*)(w + 4096 + PADMAX*8 + T_TOK*2*8);
  ushort* xb      = (ushort*)(w + 339968);
  ushort* h1      = (ushort*)(w + 339968 + (size_t)T_TOK*H_DIM*2);
  ushort* gwb     = (ushort*)(w + 339968 + (size_t)T_TOK*H_DIM*2 + (size_t)PADMAX*I_DIM*2);
  ushort* uwb     = gwb + (size_t)E_NUM*I_DIM*H_DIM;
  ushort* dwb     = uwb + (size_t)E_NUM*I_DIM*H_DIM;
  ushort* ds_out  = gwb;   // overlay: gwb/uwb are dead once gateup completes

  size_t need = 339968 + (size_t)T_TOK*H_DIM*2 + (size_t)PADMAX*I_DIM*2
              + 3ull * E_NUM*I_DIM*H_DIM * 2;
  if (ws_size < need){
    fprintf(stderr, "kernel_launch: ws too small (%zu < %zu)\n", ws_size, need);
    return;
  }

  hipMemsetAsync(out + OUT_FRAC, 0, (OUT_AVG + E_NUM - OUT_FRAC) * 4, stream);
  hipMemsetAsync(d_ws, 0, 4096, stream);
  convert4_kernel<<<NXB + 3*NWB, 256, 0, stream>>>(x, gw, uw, dwn, xb, gwb, uwb, dwb);
  router_kernel<<<T_TOK/4, 256, 0, stream>>>(x, rw, out, counts, pe, pw);
  offsets_kernel<<<1, 256, 0, stream>>>(counts, pad_off, tile_e, tile_r, hdr, s_tok, s_wt);
  scatter_kernel<<<T_TOK/256, 256, 0, stream>>>(pe, pw, pad_off, cursors, s_tok, s_wt, slot_idx);
  gateup_kernel<<<dim3(I_DIM/256, MAX_TILES), 512, 0, stream>>>(xb, gwb, uwb, s_tok, tile_e, tile_r, hdr, h1);
  down_kernel<<<dim3(H_DIM/256, MAX_TILES), 512, 0, stream>>>(h1, dwb, tile_e, tile_r, hdr, ds_out);
  combine_kernel<<<T_TOK/2, 256, 0, stream>>>(ds_out, slot_idx, s_wt, out);
  finalize_kernel<<<1, 64, 0, stream>>>(counts, out);
}